// Round 20
// baseline (542.032 us; speedup 1.0000x reference)
//
#include <hip/hip_runtime.h>
#include <hip/hip_bf16.h>

typedef unsigned short ushort_t;
typedef __attribute__((ext_vector_type(4))) float f32x4;
typedef __attribute__((ext_vector_type(8))) short bf16x8;
typedef __attribute__((ext_vector_type(8))) unsigned short us8;

#define T_TOK 4096
#define D_DIM 1024
#define FF_DIM 4096
#define NE 8
#define ESTRIDE 4194304L  // 4096*1024 elements per expert weight matrix

__device__ __forceinline__ unsigned short f2bf(float f) {
  __hip_bfloat16 h = __float2bfloat16(f);
  return __builtin_bit_cast(unsigned short, h);
}
__device__ __forceinline__ float bf2f(ushort_t u) {
  unsigned int x = ((unsigned int)u) << 16;
  return __builtin_bit_cast(float, x);
}
__device__ __forceinline__ float gelu_f(float v) {
  return 0.5f * v * (1.0f + erff(v * 0.70710678118654752440f));
}

// ---------------- pre: gate+x->bf16 [bids 0..1023] ++ W1-transpose [1024..] --
__global__ __launch_bounds__(256) void pre_kernel(
    const float* __restrict__ x, const float* __restrict__ Wg,
    const float* __restrict__ W1, const float* __restrict__ Ws1,
    int* __restrict__ cnt, int* __restrict__ tok,
    float* __restrict__ wof, int* __restrict__ rankof,
    ushort_t* __restrict__ Xbf, ushort_t* __restrict__ W1T) {
  __shared__ ushort_t tile[128][136];
  const int bid = blockIdx.x, tid = threadIdx.x;

  if (bid < 1024) {  // ---- gate: one wave per token, 4 tokens/block ----
    const int t = bid * 4 + (tid >> 6);
    const int lane = tid & 63;
    const float* xr = x + (long)t * D_DIM;
    ushort_t* xb = Xbf + (long)t * D_DIM;
    float acc[NE];
#pragma unroll
    for (int e = 0; e < NE; e++) acc[e] = 0.f;
#pragma unroll
    for (int i = 0; i < 16; i++) {
      int d = i * 64 + lane;
      float xv = xr[d];
      xb[d] = f2bf(xv);
      const float* wr = Wg + d * NE;
#pragma unroll
      for (int e = 0; e < NE; e++) acc[e] += xv * wr[e];
    }
#pragma unroll
    for (int off = 32; off > 0; off >>= 1) {
#pragma unroll
      for (int e = 0; e < NE; e++) acc[e] += __shfl_xor(acc[e], off, 64);
    }
    if (lane == 0) {
      int i0 = 0;
#pragma unroll
      for (int e = 1; e < NE; e++) if (acc[e] > acc[i0]) i0 = e;
      int i1 = -1;
#pragma unroll
      for (int e = 0; e < NE; e++) {
        if (e == i0) continue;
        if (i1 < 0 || acc[e] > acc[i1]) i1 = e;
      }
      float e1 = expf(acc[i1] - acc[i0]);
      float w0 = 1.f / (1.f + e1);
      float w1 = e1 * w0;
      int s0 = atomicAdd(&cnt[i0], 1);
      tok[i0 * T_TOK + s0] = t; wof[i0 * T_TOK + s0] = w0; rankof[i0 * T_TOK + s0] = 0;
      int s1 = atomicAdd(&cnt[i1], 1);
      tok[i1 * T_TOK + s1] = t; wof[i1 * T_TOK + s1] = w1; rankof[i1 * T_TOK + s1] = 1;
      tok[8 * T_TOK + t] = t; wof[8 * T_TOK + t] = 1.f; rankof[8 * T_TOK + t] = 0;
    }
    return;
  }

  // ---- W1 transpose tile: fp32 [1024][4096] -> bf16 [4096][1024] ----
  int tix = bid - 1024;
  if (tix >= 2304) return;
  const int e = tix >> 8;        // 9 experts x 256 tiles (8 row x 32 col)
  const int rem = tix & 255;
  const int r0 = (rem >> 5) * 128, c0 = (rem & 31) * 128;
  const float* src = (e == 8) ? Ws1 : (W1 + (long)e * 4194304);
  ushort_t* d = W1T + (long)e * ESTRIDE;
#pragma unroll
  for (int i = 0; i < 16; i++) {
    int lin = tid + i * 256;
    int r = lin >> 5, c = (lin & 31) * 4;
    float4 v = *(const float4*)(src + (long)(r0 + r) * 4096 + c0 + c);
    tile[c + 0][r] = f2bf(v.x);
    tile[c + 1][r] = f2bf(v.y);
    tile[c + 2][r] = f2bf(v.z);
    tile[c + 3][r] = f2bf(v.w);
  }
  __syncthreads();
#pragma unroll
  for (int i = 0; i < 8; i++) {
    int lin = tid + i * 256;
    int cc = lin >> 4, rp = lin & 15;
    us8 v = *(const us8*)&tile[cc][rp * 8];
    *(us8*)(d + (long)(c0 + cc) * 1024 + r0 + rp * 8) = v;
  }
}

// ---------------- build queues + base prefix (scan folded in) ---------------
__global__ void build_queue_kernel(const int* __restrict__ cnt, int* __restrict__ base,
                                   unsigned int* __restrict__ q1,
                                   unsigned int* __restrict__ q2,
                                   int* __restrict__ nq, int* __restrict__ cnt8) {
  const int e = blockIdx.x;  // 9 blocks
  int off1 = 0, off2 = 0, tot1 = 0, tot2 = 0, M = 0;
  for (int i = 0; i < 9; i++) {
    int c = (i == 8) ? T_TOK : cnt[i];
    int m = (c + 255) >> 8;
    if (i < e) { off1 += m * 16; off2 += m * 4; }
    if (i == e) M = m;
    tot1 += m * 16; tot2 += m * 4;
  }
  for (int i = threadIdx.x; i < M * 16; i += 256) {
    int my = i >> 4, nx = i & 15;
    int ms = my >> 1, mi = my & 1, ns = nx >> 2, ni = nx & 3;
    int h = M - ms * 2; if (h > 2) h = 2;
    int pos = ms * 32 + ns * (h * 4) + mi * 4 + ni;
    q1[off1 + pos] = ((unsigned)e << 16) | ((unsigned)my << 8) | (unsigned)nx;
  }
  for (int i = threadIdx.x; i < M * 4; i += 256) {
    int my = i >> 2, nx = i & 3;
    int pos = nx * M + my;  // nx-major: share B panel
    q2[off2 + pos] = ((unsigned)e << 16) | ((unsigned)my << 8) | (unsigned)nx;
  }
  if (e == 0 && threadIdx.x == 0) {
    nq[0] = tot1; nq[1] = tot2;
    int s = 0;
    for (int i = 0; i < NE; i++) { base[i] = s; s += cnt[i]; }
    base[8] = s;
    *cnt8 = T_TOK;
  }
}

// ---------------- GEMM: 256x256, 8 waves (2x4), wave 128x64 (acc[8][4]) -----
// THE ratio fix: LDS fragment bytes/step = 8 waves x (128+64)x32x2B = 96 KB
// (vs 128 KB at 16x 64x64 waves) for the same 256 MFMA -> LDS-throughput cap
// rises 20%->27% MfmaUtil. Single barrier per K-step: 4 buffers, stage tile
// t+3 AFTER the barrier (prior reads lgkm-complete before any wave's stage of
// that buffer -> race-free), vmcnt(8)/4/0 ladder, never drains mid-loop.
// __launch_bounds__(512,2): 256-reg cap (128 AGPR acc + ~80 VGPR).
// FUSE (GEMM1): bids [0,1024) GEMM ++ [1024,3328) W2 transpose (appended).
template <int K, int N, int PHASE, bool FUSE>
__global__ __launch_bounds__(512, 2) void gemm_kernel(
    const ushort_t* __restrict__ Abase, const ushort_t* __restrict__ WT,
    const float* __restrict__ bias_e, const float* __restrict__ bias_s,
    const int* __restrict__ cnt, const int* __restrict__ base,
    const int* __restrict__ tok, const float* __restrict__ wof,
    const int* __restrict__ rankof,
    const unsigned int* __restrict__ q, const int* __restrict__ nq_all,
    ushort_t* __restrict__ He, ushort_t* __restrict__ ybuf, float* __restrict__ out,
    const float* __restrict__ W2src, const float* __restrict__ Ws2src,
    ushort_t* __restrict__ W2Tdst) {
  __shared__ char smem[131072];  // 4 bufs x (A 16KB + B 16KB)
  const int tid = threadIdx.x;
  const int bid = blockIdx.x;
  const int NBLK = FUSE ? 1024 : (int)gridDim.x;

  if (FUSE && bid >= 1024) {
    // ---- appended job: 128x128 tile of W2 (R=4096, C=1024) -> W2T ----
    int tix = bid - 1024;
    if (tix >= 2304) return;
    const int e = tix >> 8;
    const int rem = tix & 255;
    const int r0 = (rem >> 3) * 128, c0 = (rem & 7) * 128;
    const float* src = (e == 8) ? Ws2src : (W2src + (long)e * 4194304);
    ushort_t* d = W2Tdst + (long)e * ESTRIDE;
    ushort_t (*tile)[136] = (ushort_t (*)[136])smem;
#pragma unroll
    for (int i = 0; i < 8; i++) {
      int lin = tid + i * 512;
      int r = lin >> 5, c = (lin & 31) * 4;
      float4 v = *(const float4*)(src + (long)(r0 + r) * 1024 + c0 + c);
      tile[c + 0][r] = f2bf(v.x);
      tile[c + 1][r] = f2bf(v.y);
      tile[c + 2][r] = f2bf(v.z);
      tile[c + 3][r] = f2bf(v.w);
    }
    __syncthreads();
#pragma unroll
    for (int i = 0; i < 4; i++) {
      int lin = tid + i * 512;
      int cc = lin >> 4, rp = lin & 15;
      us8 v = *(const us8*)&tile[cc][rp * 8];
      *(us8*)(d + (long)(c0 + cc) * 4096 + r0 + rp * 8) = v;
    }
    return;
  }

  const int nq = nq_all[PHASE - 1];
  const int chunk = NBLK >> 3;
  const int vbid = (bid < (chunk << 3)) ? ((bid & 7) * chunk + (bid >> 3)) : bid;

  const int w = tid >> 6, lane = tid & 63;
  const int wm = w >> 2, wn = w & 3;      // 2x4 wave grid; wave tile 128x64
  const int lr = lane & 15, lg = lane >> 4;
  char* const lds = smem;

  // staging: thread t covers rows (t>>2) and 128+(t>>2) of A and of B;
  // stored 16B-slot t&3 holds global chunk g = ((t&3) - ((t>>3)&3)) & 3
  const int srow = tid >> 2;                       // 0..127
  const int cg = ((tid & 3) - ((tid >> 3) & 3)) & 3;

  int offA[8], offB[4];
#pragma unroll
  for (int m = 0; m < 8; m++) {
    int r = wm * 128 + m * 16 + lr;                // A row 0..255
    offA[m] = r * 64 + (((lg + (r >> 1)) & 3) << 4);
  }
#pragma unroll
  for (int n = 0; n < 4; n++) {
    int r = wn * 64 + n * 16 + lr;                 // B row 0..255
    offB[n] = 16384 + r * 64 + (((lg + (r >> 1)) & 3) << 4);
  }

  constexpr int NT = K / 32;

#define STAGE(buf_, kk_)                                                        \
  do {                                                                          \
    char* dd_ = lds + (buf_) * 32768 + tid * 16;                                \
    __builtin_amdgcn_global_load_lds(                                           \
        (const __attribute__((address_space(1))) void*)(pA0 + (kk_)),           \
        (__attribute__((address_space(3))) void*)(dd_), 16, 0, 0);              \
    __builtin_amdgcn_global_load_lds(                                           \
        (const __attribute__((address_space(1))) void*)(pA1 + (kk_)),           \
        (__attribute__((address_space(3))) void*)(dd_ + 8192), 16, 0, 0);       \
    __builtin_amdgcn_global_load_lds(                                           \
        (const __attribute__((address_space(1))) void*)(pB0 + (kk_)),           \
        (__attribute__((address_space(3))) void*)(dd_ + 16384), 16, 0, 0);      \
    __builtin_amdgcn_global_load_lds(                                           \
        (const __attribute__((address_space(1))) void*)(pB1 + (kk_)),           \
        (__attribute__((address_space(3))) void*)(dd_ + 24576), 16, 0, 0);      \
  } while (0)

  for (int it = vbid; it < nq; it += NBLK) {
    const unsigned int item = q[it];
    const int e = item >> 16;
    const int m0 = ((item >> 8) & 0xff) * 256;
    const int n0 = (item & 0xff) * 256;
    const int count = cnt[e];

    long arow0, arow1;
    {
      int rr = m0 + srow;
      int rc = (rr < count) ? rr : 0;
      arow0 = (PHASE == 1) ? tok[e * T_TOK + rc] : ((long)base[e] + rc);
      rr = m0 + 128 + srow;
      rc = (rr < count) ? rr : 0;
      arow1 = (PHASE == 1) ? tok[e * T_TOK + rc] : ((long)base[e] + rc);
    }
    const ushort_t* pA0 = Abase + arow0 * (long)K + cg * 8;
    const ushort_t* pA1 = Abase + arow1 * (long)K + cg * 8;
    const ushort_t* pB0 = WT + (long)e * ESTRIDE + (long)(n0 + srow) * K + cg * 8;
    const ushort_t* pB1 = pB0 + 128L * K;

    f32x4 acc[8][4] = {};

    __builtin_amdgcn_s_barrier();        // prev item's reads all complete
    asm volatile("" ::: "memory");
    STAGE(0, 0); STAGE(1, 32); STAGE(2, 64);   // 3 tiles in flight

    for (int t = 0; t < NT; t++) {
      if (t + 2 < NT)      asm volatile("s_waitcnt vmcnt(8)" ::: "memory");
      else if (t + 1 < NT) asm volatile("s_waitcnt vmcnt(4)" ::: "memory");
      else                 asm volatile("s_waitcnt vmcnt(0)" ::: "memory");
      __builtin_amdgcn_s_barrier();      // single barrier: tile t confirmed;
      asm volatile("" ::: "memory");     // prior reads of buf (t+3)&3 done
      if (t + 3 < NT) STAGE((t + 3) & 3, (t + 3) * 32);

      const char* aB = lds + (t & 3) * 32768;
      bf16x8 av[8], bv[4];
#pragma unroll
      for (int m = 0; m < 8; m++) av[m] = *(const bf16x8*)(aB + offA[m]);
#pragma unroll
      for (int n = 0; n < 4; n++) bv[n] = *(const bf16x8*)(aB + offB[n]);
#pragma unroll
      for (int m = 0; m < 8; m++)
#pragma unroll
        for (int n = 0; n < 4; n++)
          acc[m][n] = __builtin_amdgcn_mfma_f32_16x16x32_bf16(av[m], bv[n], acc[m][n], 0, 0, 0);
    }

    const float* bias = (e == NE) ? bias_s : (bias_e + (long)e * N);
#pragma unroll
    for (int m = 0; m < 8; m++) {
#pragma unroll
      for (int j = 0; j < 4; j++) {
        int rloc = wm * 128 + m * 16 + lg * 4 + j;  // D row = (lane>>4)*4 + reg
        int rrr = m0 + rloc;
        if (rrr >= count) continue;
        if (PHASE == 1) {
          long orow = (long)base[e] + rrr;
#pragma unroll
          for (int n = 0; n < 4; n++) {
            int col = n0 + wn * 64 + n * 16 + lr;  // D col = lane&15
            float v = acc[m][n][j] + bias[col];
            He[orow * FF_DIM + col] = f2bf(gelu_f(v));
          }
        } else {
          int tt = tok[e * T_TOK + rrr];
          if (e == NE) {  // shared FFN -> d_out directly (fp32)
#pragma unroll
            for (int n = 0; n < 4; n++) {
              int col = n0 + wn * 64 + n * 16 + lr;
              out[(long)tt * D_DIM + col] = acc[m][n][j] + bias[col];
            }
          } else {        // routed experts -> bf16 rank plane
            float wgt = wof[e * T_TOK + rrr];
            int rk = rankof[e * T_TOK + rrr];
            ushort_t* dst = ybuf + (long)rk * ((long)T_TOK * D_DIM) + (long)tt * D_DIM;
#pragma unroll
            for (int n = 0; n < 4; n++) {
              int col = n0 + wn * 64 + n * 16 + lr;
              dst[col] = f2bf(wgt * (acc[m][n][j] + bias[col]));
            }
          }
        }
      }
    }
  }
#undef STAGE
}

// ---------------- final: out += y_rank0 + y_rank1 (bf16 planes) -------------
__global__ void final_add_kernel(float* __restrict__ out, const ushort_t* __restrict__ ybuf) {
  long i = ((long)blockIdx.x * 256 + threadIdx.x) * 8;
  float4 a0 = *(const float4*)(out + i);
  float4 a1 = *(const float4*)(out + i + 4);
  us8 b = *(const us8*)(ybuf + i);
  us8 c = *(const us8*)(ybuf + (long)T_TOK * D_DIM + i);
  float r[8];
#pragma unroll
  for (int k = 0; k < 8; k++) r[k] = bf2f(b[k]) + bf2f(c[k]);
  a0.x += r[0]; a0.y += r[1]; a0.z += r[2]; a0.w += r[3];
  a1.x += r[4]; a1.y += r[5]; a1.z += r[6]; a1.w += r[7];
  *(float4*)(out + i) = a0;
  *(float4*)(out + i + 4) = a1;
}

extern "C" void kernel_launch(void* const* d_in, const int* in_sizes, int n_in,
                              void* d_out, int out_size, void* d_ws, size_t ws_size,
                              hipStream_t stream) {
  (void)in_sizes; (void)n_in; (void)out_size; (void)ws_size;
  const float* x   = (const float*)d_in[0];
  const float* Wg  = (const float*)d_in[1];
  const float* W1  = (const float*)d_in[2];
  const float* b1  = (const float*)d_in[3];
  const float* W2  = (const float*)d_in[4];
  const float* b2  = (const float*)d_in[5];
  const float* Ws1 = (const float*)d_in[6];
  const float* bs1 = (const float*)d_in[7];
  const float* Ws2 = (const float*)d_in[8];
  const float* bs2 = (const float*)d_in[9];
  float* out = (float*)d_out;

  char* ws = (char*)d_ws;
  int*      cnt    = (int*)(ws + 0);
  int*      base   = (int*)(ws + 64);
  int*      tok    = (int*)(ws + 256);
  float*    wof    = (float*)(ws + 256 + 147456);
  int*      rankof = (int*)(ws + 256 + 2 * 147456);
  ushort_t* Xbf    = (ushort_t*)(ws + 442624);
  ushort_t* W1T    = (ushort_t*)(ws + 8831232);
  ushort_t* W2T    = (ushort_t*)(ws + 84328704);
  ushort_t* He     = (ushort_t*)(ws + 159826176);
  int*      nq     = (int*)(ws + 260489472);
  unsigned int* q1 = (unsigned int*)(ws + 260489536);
  unsigned int* q2 = (unsigned int*)(ws + 260489536 + 32768);
  ushort_t* ybuf   = (ushort_t*)(ws + 261538048);     // 2 x [4096][1024] bf16

  hipMemsetAsync(cnt, 0, 64, stream);
  pre_kernel<<<3328, 256, 0, stream>>>(x, Wg, W1, Ws1, cnt, tok, wof, rankof, Xbf, W1T);
  build_queue_kernel<<<9, 256, 0, stream>>>(cnt, base, q1, q2, nq, &cnt[8]);
  // GEMM1 (bids 0..1023) ++ W2 transpose (bids 1024..3327)
  gemm_kernel<1024, 4096, 1, true><<<3328, 512, 0, stream>>>(
      Xbf, W1T, b1, bs1, cnt, base, tok, wof, rankof, q1, nq, He, ybuf, out,
      W2, Ws2, W2T);
  gemm_kernel<4096, 1024, 2, false><<<256, 512, 0, stream>>>(
      He, W2T, b2, bs2, cnt, base, tok, wof, rankof, q2, nq, He, ybuf, out,
      nullptr, nullptr, nullptr);
  final_add_kernel<<<2048, 256, 0, stream>>>(out, ybuf);
}

// Round 21
// 504.087 us; speedup vs baseline: 1.0753x; 1.0753x over previous
//
#include <hip/hip_runtime.h>
#include <hip/hip_bf16.h>

typedef unsigned short ushort_t;
typedef __attribute__((ext_vector_type(4))) float f32x4;
typedef __attribute__((ext_vector_type(8))) short bf16x8;
typedef __attribute__((ext_vector_type(8))) unsigned short us8;

#define T_TOK 4096
#define D_DIM 1024
#define FF_DIM 4096
#define NE 8
#define ESTRIDE 4194304L  // 4096*1024 elements per expert weight matrix

__device__ __forceinline__ unsigned short f2bf(float f) {
  __hip_bfloat16 h = __float2bfloat16(f);
  return __builtin_bit_cast(unsigned short, h);
}
__device__ __forceinline__ float bf2f(ushort_t u) {
  unsigned int x = ((unsigned int)u) << 16;
  return __builtin_bit_cast(float, x);
}
__device__ __forceinline__ float gelu_f(float v) {
  return 0.5f * v * (1.0f + erff(v * 0.70710678118654752440f));
}

// ---------------- pre: gate+x->bf16 [bids 0..1023] ++ W1-transpose [1024..] --
__global__ __launch_bounds__(256) void pre_kernel(
    const float* __restrict__ x, const float* __restrict__ Wg,
    const float* __restrict__ W1, const float* __restrict__ Ws1,
    int* __restrict__ cnt, int* __restrict__ tok,
    float* __restrict__ wof, int* __restrict__ rankof,
    ushort_t* __restrict__ Xbf, ushort_t* __restrict__ W1T) {
  __shared__ ushort_t tile[128][136];
  const int bid = blockIdx.x, tid = threadIdx.x;

  if (bid < 1024) {  // ---- gate: one wave per token, 4 tokens/block ----
    const int t = bid * 4 + (tid >> 6);
    const int lane = tid & 63;
    const float* xr = x + (long)t * D_DIM;
    ushort_t* xb = Xbf + (long)t * D_DIM;
    float acc[NE];
#pragma unroll
    for (int e = 0; e < NE; e++) acc[e] = 0.f;
#pragma unroll
    for (int i = 0; i < 16; i++) {
      int d = i * 64 + lane;
      float xv = xr[d];
      xb[d] = f2bf(xv);
      const float* wr = Wg + d * NE;
#pragma unroll
      for (int e = 0; e < NE; e++) acc[e] += xv * wr[e];
    }
#pragma unroll
    for (int off = 32; off > 0; off >>= 1) {
#pragma unroll
      for (int e = 0; e < NE; e++) acc[e] += __shfl_xor(acc[e], off, 64);
    }
    if (lane == 0) {
      int i0 = 0;
#pragma unroll
      for (int e = 1; e < NE; e++) if (acc[e] > acc[i0]) i0 = e;
      int i1 = -1;
#pragma unroll
      for (int e = 0; e < NE; e++) {
        if (e == i0) continue;
        if (i1 < 0 || acc[e] > acc[i1]) i1 = e;
      }
      float e1 = expf(acc[i1] - acc[i0]);
      float w0 = 1.f / (1.f + e1);
      float w1 = e1 * w0;
      int s0 = atomicAdd(&cnt[i0], 1);
      tok[i0 * T_TOK + s0] = t; wof[i0 * T_TOK + s0] = w0; rankof[i0 * T_TOK + s0] = 0;
      int s1 = atomicAdd(&cnt[i1], 1);
      tok[i1 * T_TOK + s1] = t; wof[i1 * T_TOK + s1] = w1; rankof[i1 * T_TOK + s1] = 1;
      tok[8 * T_TOK + t] = t; wof[8 * T_TOK + t] = 1.f; rankof[8 * T_TOK + t] = 0;
    }
    return;
  }

  // ---- W1 transpose tile: fp32 [1024][4096] -> bf16 [4096][1024] ----
  int tix = bid - 1024;
  if (tix >= 2304) return;
  const int e = tix >> 8;        // 9 experts x 256 tiles (8 row x 32 col)
  const int rem = tix & 255;
  const int r0 = (rem >> 5) * 128, c0 = (rem & 31) * 128;
  const float* src = (e == 8) ? Ws1 : (W1 + (long)e * 4194304);
  ushort_t* d = W1T + (long)e * ESTRIDE;
#pragma unroll
  for (int i = 0; i < 16; i++) {
    int lin = tid + i * 256;
    int r = lin >> 5, c = (lin & 31) * 4;
    float4 v = *(const float4*)(src + (long)(r0 + r) * 4096 + c0 + c);
    tile[c + 0][r] = f2bf(v.x);
    tile[c + 1][r] = f2bf(v.y);
    tile[c + 2][r] = f2bf(v.z);
    tile[c + 3][r] = f2bf(v.w);
  }
  __syncthreads();
#pragma unroll
  for (int i = 0; i < 8; i++) {
    int lin = tid + i * 256;
    int cc = lin >> 4, rp = lin & 15;
    us8 v = *(const us8*)&tile[cc][rp * 8];
    *(us8*)(d + (long)(c0 + cc) * 1024 + r0 + rp * 8) = v;
  }
}

// ---------------- build queues + base prefix (scan folded in) ---------------
__global__ void build_queue_kernel(const int* __restrict__ cnt, int* __restrict__ base,
                                   unsigned int* __restrict__ q1,
                                   unsigned int* __restrict__ q2,
                                   int* __restrict__ nq, int* __restrict__ cnt8) {
  const int e = blockIdx.x;  // 9 blocks
  int off1 = 0, off2 = 0, tot1 = 0, tot2 = 0, M = 0;
  for (int i = 0; i < 9; i++) {
    int c = (i == 8) ? T_TOK : cnt[i];
    int m = (c + 255) >> 8;
    if (i < e) { off1 += m * 16; off2 += m * 4; }
    if (i == e) M = m;
    tot1 += m * 16; tot2 += m * 4;
  }
  for (int i = threadIdx.x; i < M * 16; i += 256) {
    int my = i >> 4, nx = i & 15;
    int ms = my >> 1, mi = my & 1, ns = nx >> 2, ni = nx & 3;
    int h = M - ms * 2; if (h > 2) h = 2;
    int pos = ms * 32 + ns * (h * 4) + mi * 4 + ni;
    q1[off1 + pos] = ((unsigned)e << 16) | ((unsigned)my << 8) | (unsigned)nx;
  }
  for (int i = threadIdx.x; i < M * 4; i += 256) {
    int my = i >> 2, nx = i & 3;
    int pos = nx * M + my;  // nx-major: share B panel
    q2[off2 + pos] = ((unsigned)e << 16) | ((unsigned)my << 8) | (unsigned)nx;
  }
  if (e == 0 && threadIdx.x == 0) {
    nq[0] = tot1; nq[1] = tot2;
    int s = 0;
    for (int i = 0; i < NE; i++) { base[i] = s; s += cnt[i]; }
    base[8] = s;
    *cnt8 = T_TOK;
  }
}

// ---------------- GEMM: 256x256, 16 waves, BK=32, counted vmcnt -------------
// Best-measured configuration (r14/r19, 504.4 us). FUSE (GEMM1): bids
// [0,1024) = GEMM (all XCD residues); bids [1024,3328) = W2 128x128
// transpose tiles (appended, never stride-interleaved).
// __launch_bounds__(1024,1): reg cap 128 (VGPR 60 + 64 acc AGPR).
template <int K, int N, int PHASE, bool FUSE>
__global__ __launch_bounds__(1024, 1) void gemm_kernel(
    const ushort_t* __restrict__ Abase, const ushort_t* __restrict__ WT,
    const float* __restrict__ bias_e, const float* __restrict__ bias_s,
    const int* __restrict__ cnt, const int* __restrict__ base,
    const int* __restrict__ tok, const float* __restrict__ wof,
    const int* __restrict__ rankof,
    const unsigned int* __restrict__ q, const int* __restrict__ nq_all,
    ushort_t* __restrict__ He, ushort_t* __restrict__ ybuf, float* __restrict__ out,
    const float* __restrict__ W2src, const float* __restrict__ Ws2src,
    ushort_t* __restrict__ W2Tdst) {
  __shared__ char smem[65536];
  const int tid = threadIdx.x;
  const int bid = blockIdx.x;
  const int NBLK = FUSE ? 1024 : (int)gridDim.x;

  if (FUSE && bid >= 1024) {
    // ---- appended job: 128x128 tile of W2 (R=4096, C=1024) -> W2T ----
    int tix = bid - 1024;
    if (tix >= 2304) return;
    const int e = tix >> 8;
    const int rem = tix & 255;
    const int r0 = (rem >> 3) * 128, c0 = (rem & 7) * 128;
    const float* src = (e == 8) ? Ws2src : (W2src + (long)e * 4194304);
    ushort_t* d = W2Tdst + (long)e * ESTRIDE;
    ushort_t (*tile)[136] = (ushort_t (*)[136])smem;
#pragma unroll
    for (int i = 0; i < 4; i++) {
      int lin = tid + i * 1024;
      int r = lin >> 5, c = (lin & 31) * 4;
      float4 v = *(const float4*)(src + (long)(r0 + r) * 1024 + c0 + c);
      tile[c + 0][r] = f2bf(v.x);
      tile[c + 1][r] = f2bf(v.y);
      tile[c + 2][r] = f2bf(v.z);
      tile[c + 3][r] = f2bf(v.w);
    }
    __syncthreads();
#pragma unroll
    for (int i = 0; i < 2; i++) {
      int lin = tid + i * 1024;
      int cc = lin >> 4, rp = lin & 15;
      us8 v = *(const us8*)&tile[cc][rp * 8];
      *(us8*)(d + (long)(c0 + cc) * 4096 + r0 + rp * 8) = v;
    }
    return;
  }

  const int nq = nq_all[PHASE - 1];
  const int chunk = NBLK >> 3;
  const int vbid = (bid < (chunk << 3)) ? ((bid & 7) * chunk + (bid >> 3)) : bid;

  const int w = tid >> 6, lane = tid & 63;
  const int wm = w >> 2, wn = w & 3;      // 4x4 wave grid; wave tile 64x64
  const int lr = lane & 15, lg = lane >> 4;
  char* const lds = smem;

  const int srow = tid >> 2;  // 0..255
  const int cg = ((tid & 3) - (srow >> 1)) & 3;  // inverse-swizzled k-chunk

  int offA[4], offB[4];
#pragma unroll
  for (int m = 0; m < 4; m++) {
    int r = wm * 64 + m * 16 + lr;
    offA[m] = r * 64 + (((lg + (r >> 1)) & 3) << 4);
  }
#pragma unroll
  for (int n = 0; n < 4; n++) {
    int r = wn * 64 + n * 16 + lr;
    offB[n] = r * 64 + (((lg + (r >> 1)) & 3) << 4);
  }

  constexpr int NT = K / 32;

#define STAGE(buf_, kk_)                                                        \
  do {                                                                          \
    char* dd_ = lds + (buf_) * 32768 + tid * 16;                                \
    __builtin_amdgcn_global_load_lds(                                           \
        (const __attribute__((address_space(1))) void*)(pA + (kk_)),            \
        (__attribute__((address_space(3))) void*)(dd_), 16, 0, 0);              \
    __builtin_amdgcn_global_load_lds(                                           \
        (const __attribute__((address_space(1))) void*)(pB + (kk_)),            \
        (__attribute__((address_space(3))) void*)(dd_ + 16384), 16, 0, 0);      \
  } while (0)

  for (int it = vbid; it < nq; it += NBLK) {
    const unsigned int item = q[it];
    const int e = item >> 16;
    const int m0 = ((item >> 8) & 0xff) * 256;
    const int n0 = (item & 0xff) * 256;
    const int count = cnt[e];

    int rr = m0 + srow;
    int rc = (rr < count) ? rr : 0;  // clamp OOB rows
    long arow;
    if (PHASE == 1) arow = tok[e * T_TOK + rc];
    else            arow = (long)base[e] + rc;
    const ushort_t* pA = Abase + arow * (long)K + cg * 8;
    const ushort_t* pB = WT + (long)e * ESTRIDE + (long)(n0 + srow) * K + cg * 8;

    f32x4 acc[4][4] = {};

    __builtin_amdgcn_s_barrier();            // prev item's last reads done
    asm volatile("" ::: "memory");
    STAGE(0, 0);

    for (int t = 0; t < NT; t++) {
      if (t + 1 < NT) {
        STAGE((t + 1) & 1, (t + 1) * 32);
        asm volatile("s_waitcnt vmcnt(2)" ::: "memory");  // tile t resident
      } else {
        asm volatile("s_waitcnt vmcnt(0)" ::: "memory");
      }
      __builtin_amdgcn_s_barrier();          // all waves confirm tile t
      asm volatile("" ::: "memory");

      const char* aB = lds + (t & 1) * 32768;
      const char* bB = aB + 16384;
      bf16x8 av[4], bv[4];
#pragma unroll
      for (int m = 0; m < 4; m++) av[m] = *(const bf16x8*)(aB + offA[m]);
#pragma unroll
      for (int n = 0; n < 4; n++) bv[n] = *(const bf16x8*)(bB + offB[n]);
#pragma unroll
      for (int m = 0; m < 4; m++)
#pragma unroll
        for (int n = 0; n < 4; n++)
          acc[m][n] = __builtin_amdgcn_mfma_f32_16x16x32_bf16(av[m], bv[n], acc[m][n], 0, 0, 0);

      __builtin_amdgcn_s_barrier();          // reads(t) done before overwrite
      asm volatile("" ::: "memory");
    }

    const float* bias = (e == NE) ? bias_s : (bias_e + (long)e * N);
#pragma unroll
    for (int m = 0; m < 4; m++) {
#pragma unroll
      for (int j = 0; j < 4; j++) {
        int rloc = wm * 64 + m * 16 + lg * 4 + j;  // D row = (lane>>4)*4 + reg
        int rrr = m0 + rloc;
        if (rrr >= count) continue;
        if (PHASE == 1) {
          long orow = (long)base[e] + rrr;
#pragma unroll
          for (int n = 0; n < 4; n++) {
            int col = n0 + wn * 64 + n * 16 + lr;  // D col = lane&15
            float v = acc[m][n][j] + bias[col];
            He[orow * FF_DIM + col] = f2bf(gelu_f(v));
          }
        } else {
          int tt = tok[e * T_TOK + rrr];
          if (e == NE) {  // shared FFN -> d_out directly (fp32)
#pragma unroll
            for (int n = 0; n < 4; n++) {
              int col = n0 + wn * 64 + n * 16 + lr;
              out[(long)tt * D_DIM + col] = acc[m][n][j] + bias[col];
            }
          } else {        // routed experts -> bf16 rank plane
            float wgt = wof[e * T_TOK + rrr];
            int rk = rankof[e * T_TOK + rrr];
            ushort_t* dst = ybuf + (long)rk * ((long)T_TOK * D_DIM) + (long)tt * D_DIM;
#pragma unroll
            for (int n = 0; n < 4; n++) {
              int col = n0 + wn * 64 + n * 16 + lr;
              dst[col] = f2bf(wgt * (acc[m][n][j] + bias[col]));
            }
          }
        }
      }
    }
  }
#undef STAGE
}

// ---------------- final: out += y_rank0 + y_rank1 (bf16 planes) -------------
__global__ void final_add_kernel(float* __restrict__ out, const ushort_t* __restrict__ ybuf) {
  long i = ((long)blockIdx.x * 256 + threadIdx.x) * 8;
  float4 a0 = *(const float4*)(out + i);
  float4 a1 = *(const float4*)(out + i + 4);
  us8 b = *(const us8*)(ybuf + i);
  us8 c = *(const us8*)(ybuf + (long)T_TOK * D_DIM + i);
  float r[8];
#pragma unroll
  for (int k = 0; k < 8; k++) r[k] = bf2f(b[k]) + bf2f(c[k]);
  a0.x += r[0]; a0.y += r[1]; a0.z += r[2]; a0.w += r[3];
  a1.x += r[4]; a1.y += r[5]; a1.z += r[6]; a1.w += r[7];
  *(float4*)(out + i) = a0;
  *(float4*)(out + i + 4) = a1;
}

extern "C" void kernel_launch(void* const* d_in, const int* in_sizes, int n_in,
                              void* d_out, int out_size, void* d_ws, size_t ws_size,
                              hipStream_t stream) {
  (void)in_sizes; (void)n_in; (void)out_size; (void)ws_size;
  const float* x   = (const float*)d_in[0];
  const float* Wg  = (const float*)d_in[1];
  const float* W1  = (const float*)d_in[2];
  const float* b1  = (const float*)d_in[3];
  const float* W2  = (const float*)d_in[4];
  const float* b2  = (const float*)d_in[5];
  const float* Ws1 = (const float*)d_in[6];
  const float* bs1 = (const float*)d_in[7];
  const float* Ws2 = (const float*)d_in[8];
  const float* bs2 = (const float*)d_in[9];
  float* out = (float*)d_out;

  char* ws = (char*)d_ws;
  int*      cnt    = (int*)(ws + 0);                  // cnt[0..7]; cnt[8] = +32B
  int*      base   = (int*)(ws + 64);
  int*      tok    = (int*)(ws + 256);
  float*    wof    = (float*)(ws + 256 + 147456);
  int*      rankof = (int*)(ws + 256 + 2 * 147456);
  ushort_t* Xbf    = (ushort_t*)(ws + 442624);
  ushort_t* W1T    = (ushort_t*)(ws + 8831232);
  ushort_t* W2T    = (ushort_t*)(ws + 84328704);
  ushort_t* He     = (ushort_t*)(ws + 159826176);
  int*      nq     = (int*)(ws + 260489472);
  unsigned int* q1 = (unsigned int*)(ws + 260489536);
  unsigned int* q2 = (unsigned int*)(ws + 260489536 + 32768);
  ushort_t* ybuf   = (ushort_t*)(ws + 261538048);     // 2 x [4096][1024] bf16

  hipMemsetAsync(cnt, 0, 64, stream);
  pre_kernel<<<3328, 256, 0, stream>>>(x, Wg, W1, Ws1, cnt, tok, wof, rankof, Xbf, W1T);
  build_queue_kernel<<<9, 256, 0, stream>>>(cnt, base, q1, q2, nq, &cnt[8]);
  // GEMM1 (bids 0..1023) ++ W2 transpose (bids 1024..3327)
  gemm_kernel<1024, 4096, 1, true><<<3328, 1024, 0, stream>>>(
      Xbf, W1T, b1, bs1, cnt, base, tok, wof, rankof, q1, nq, He, ybuf, out,
      W2, Ws2, W2T);
  gemm_kernel<4096, 1024, 2, false><<<256, 1024, 0, stream>>>(
      He, W2T, b2, bs2, cnt, base, tok, wof, rankof, q2, nq, He, ybuf, out,
      nullptr, nullptr, nullptr);
  final_add_kernel<<<2048, 256, 0, stream>>>(out, ybuf);
}